// Round 1
// baseline (1046.720 us; speedup 1.0000x reference)
//
#include <hip/hip_runtime.h>

// Problem constants (from reference setup_inputs)
#define BB 32     // batch
#define TD 256    // t_dim
#define HD 512    // h_dim
#define MM 128    // M (words)
#define NN 4096   // h*w

// ---------------------------------------------------------------------------
// Kernel 1: Wp[b][h][m] = sum_t head_w[h][t] * W[b][t][m]
// One block per (64-h tile, batch). 256 threads, thread computes 8h x 4m.
// ---------------------------------------------------------------------------
__global__ __launch_bounds__(256, 2) void wp_kernel(
    const float* __restrict__ Wmat,     // [B][TD][MM]
    const float* __restrict__ head_w,   // [HD][TD]
    float* __restrict__ Wp)             // [B][HD][MM]
{
    const int tid = threadIdx.x;
    const int tx = tid & 31;            // m group: m = tx*4 + c
    const int ty = tid >> 5;            // h group: h = ty*8 + r
    const int b  = blockIdx.y;
    const int h0 = blockIdx.x * 64;

    __shared__ float s_hw[64][64];      // [h][t]
    __shared__ float s_w[64][128];      // [t][m]

    float acc[8][4];
#pragma unroll
    for (int r = 0; r < 8; ++r)
#pragma unroll
        for (int c = 0; c < 4; ++c) acc[r][c] = 0.f;

    for (int t0 = 0; t0 < TD; t0 += 64) {
        // stage head_w tile (rows contiguous in t)
#pragma unroll
        for (int k = 0; k < 4; ++k) {
            int i = (tid >> 4) + 16 * k;
            int j = (tid & 15) * 4;
            *(float4*)&s_hw[i][j] = *(const float4*)&head_w[(h0 + i) * TD + t0 + j];
        }
        // stage W tile (rows contiguous in m)
#pragma unroll
        for (int k = 0; k < 8; ++k) {
            int i = (tid >> 5) + 8 * k;
            *(float4*)&s_w[i][(tid & 31) * 4] =
                *(const float4*)&Wmat[((b * TD) + t0 + i) * MM + (tid & 31) * 4];
        }
        __syncthreads();
#pragma unroll 4
        for (int tt = 0; tt < 64; ++tt) {
            float b4[4];
            *(float4*)b4 = *(const float4*)&s_w[tt][tx * 4];
#pragma unroll
            for (int r = 0; r < 8; ++r) {
                float a = s_hw[ty * 8 + r][tt];   // 2 addrs/wave -> broadcast, free
#pragma unroll
                for (int c = 0; c < 4; ++c) acc[r][c] += a * b4[c];
            }
        }
        __syncthreads();
    }
#pragma unroll
    for (int r = 0; r < 8; ++r) {
        *(float4*)&Wp[((b * HD) + h0 + ty * 8 + r) * MM + tx * 4] =
            make_float4(acc[r][0], acc[r][1], acc[r][2], acc[r][3]);
    }
}

// ---------------------------------------------------------------------------
// Kernel 2: fused scores(K=512) -> softmax(M=128) -> PV(K=128) -> transposed
// store. One block per (b, 64-row n-tile). 256 threads.
// LDS: phase 1 uses Ht[64][64] + Wt[64][128] (12288 floats).
//      phase 2 uses A_s[64][128] + Wt2[64][128], XOR-bank-swizzled
//      (elem (row,m) at row*128 + (m ^ (row&31))) -> conflict-free b32 reads.
// Total LDS = 16384 floats = 64 KB -> 2 blocks/CU.
// ---------------------------------------------------------------------------
__global__ __launch_bounds__(256, 2) void fused_kernel(
    const float* __restrict__ H,        // [B][HD][NN]
    const float* __restrict__ Wp,       // [B][HD][MM]
    float* __restrict__ out)            // [B][HD][NN]
{
    const int tid = threadIdx.x;
    const int tx = tid & 31;            // m group: m = tx*4 + c
    const int ty = tid >> 5;            // n group: n = ty*8 + r (phase 1)
    const int b  = blockIdx.x >> 6;
    const int n0 = (blockIdx.x & 63) * 64;

    __shared__ float lds[16384];
    float* Ht = lds;                    // [64][64]   (phase 1) [h][n]
    float* Wt = lds + 4096;             // [64][128]  (phase 1) [h][m]

    const float* Hb  = H  + ((size_t)b * HD) * NN + n0;
    const float* Wpb = Wp + ((size_t)b * HD) * MM;

    float acc[8][4];
#pragma unroll
    for (int r = 0; r < 8; ++r)
#pragma unroll
        for (int c = 0; c < 4; ++c) acc[r][c] = 0.f;

    // ---- Phase 1: S[n][m] = sum_h H[h][n] * Wp[h][m], K chunked by 64 ----
    for (int h0 = 0; h0 < HD; h0 += 64) {
#pragma unroll
        for (int k = 0; k < 4; ++k) {
            int i = (tid >> 4) + 16 * k;
            *(float4*)&Ht[i * 64 + (tid & 15) * 4] =
                *(const float4*)&Hb[(size_t)(h0 + i) * NN + (tid & 15) * 4];
        }
#pragma unroll
        for (int k = 0; k < 8; ++k) {
            int i = (tid >> 5) + 8 * k;
            *(float4*)&Wt[i * 128 + (tid & 31) * 4] =
                *(const float4*)&Wpb[(h0 + i) * MM + (tid & 31) * 4];
        }
        __syncthreads();
#pragma unroll 4
        for (int hh = 0; hh < 64; ++hh) {
            float a8[8], b4[4];
            *(float4*)&a8[0] = *(const float4*)&Ht[hh * 64 + ty * 8];      // broadcast
            *(float4*)&a8[4] = *(const float4*)&Ht[hh * 64 + ty * 8 + 4];  // broadcast
            *(float4*)&b4[0] = *(const float4*)&Wt[hh * 128 + tx * 4];     // canonical, free
#pragma unroll
            for (int r = 0; r < 8; ++r)
#pragma unroll
                for (int c = 0; c < 4; ++c) acc[r][c] += a8[r] * b4[c];
        }
        __syncthreads();
    }

    // ---- Softmax over m (row n = ty*8+r spread across the 32 tx lanes) ----
#pragma unroll
    for (int r = 0; r < 8; ++r) {
        float mx = fmaxf(fmaxf(acc[r][0], acc[r][1]), fmaxf(acc[r][2], acc[r][3]));
#pragma unroll
        for (int off = 16; off >= 1; off >>= 1)
            mx = fmaxf(mx, __shfl_xor(mx, off));
        float s = 0.f;
#pragma unroll
        for (int c = 0; c < 4; ++c) { acc[r][c] = __expf(acc[r][c] - mx); s += acc[r][c]; }
#pragma unroll
        for (int off = 16; off >= 1; off >>= 1)
            s += __shfl_xor(s, off);
        float inv = 1.f / s;
#pragma unroll
        for (int c = 0; c < 4; ++c) acc[r][c] *= inv;
    }

    // ---- Store A to LDS (XOR-swizzled). Phase-1 loop ended in a barrier. ----
    float* A_s = lds;                   // [64][128] swizzled
    float* Wt2 = lds + 8192;            // [64][128] swizzled
#pragma unroll
    for (int r = 0; r < 8; ++r) {
        int n = ty * 8 + r;
        int base = n * 128, msk = n & 31;
#pragma unroll
        for (int c = 0; c < 4; ++c)
            A_s[base + ((tx * 4 + c) ^ msk)] = acc[r][c];
    }

    // ---- Phase 2: out[h][n] = sum_m Wp[h][m] * A[n][m], h chunked by 64 ----
    const int nn  = (tid & 15) * 4;     // n offset in tile (4 rows)
    const int hh4 = (tid >> 4) * 4;     // h offset in chunk (4 rows)
    float* outb = out + ((size_t)b * HD) * NN + n0;

    int abase[4], amask[4], wbase[4], wmask[4];
#pragma unroll
    for (int j = 0; j < 4; ++j) { abase[j] = (nn + j) * 128; amask[j] = (nn + j) & 31; }
#pragma unroll
    for (int i = 0; i < 4; ++i) { wbase[i] = (hh4 + i) * 128; wmask[i] = (hh4 + i) & 31; }

    for (int hc = 0; hc < HD; hc += 64) {
        // stage Wp chunk, swizzled
#pragma unroll
        for (int k = 0; k < 8; ++k) {
            int i = (tid >> 5) + 8 * k;
            float4 v = *(const float4*)&Wpb[(hc + i) * MM + (tid & 31) * 4];
            int base = i * 128, msk = i & 31, m0 = (tid & 31) * 4;
            Wt2[base + ((m0 + 0) ^ msk)] = v.x;
            Wt2[base + ((m0 + 1) ^ msk)] = v.y;
            Wt2[base + ((m0 + 2) ^ msk)] = v.z;
            Wt2[base + ((m0 + 3) ^ msk)] = v.w;
        }
        __syncthreads();

        float accB[4][4];
#pragma unroll
        for (int i = 0; i < 4; ++i)
#pragma unroll
            for (int j = 0; j < 4; ++j) accB[i][j] = 0.f;

#pragma unroll 4
        for (int m = 0; m < 128; ++m) {
            float w4[4], a4[4];
#pragma unroll
            for (int i = 0; i < 4; ++i) w4[i] = Wt2[wbase[i] + (m ^ wmask[i])];
#pragma unroll
            for (int j = 0; j < 4; ++j) a4[j] = A_s[abase[j] + (m ^ amask[j])];
#pragma unroll
            for (int i = 0; i < 4; ++i)
#pragma unroll
                for (int j = 0; j < 4; ++j) accB[i][j] += w4[i] * a4[j];
        }
#pragma unroll
        for (int i = 0; i < 4; ++i)
            *(float4*)&outb[(size_t)(hc + hh4 + i) * NN + nn] =
                make_float4(accB[i][0], accB[i][1], accB[i][2], accB[i][3]);
        __syncthreads();   // before next chunk overwrites Wt2
    }
}

// ---------------------------------------------------------------------------
extern "C" void kernel_launch(void* const* d_in, const int* in_sizes, int n_in,
                              void* d_out, int out_size, void* d_ws, size_t ws_size,
                              hipStream_t stream)
{
    (void)in_sizes; (void)n_in; (void)out_size; (void)ws_size;
    const float* H      = (const float*)d_in[0];   // [32][512][64][64]
    const float* Wmat   = (const float*)d_in[1];   // [32][256][128]
    const float* head_w = (const float*)d_in[2];   // [512][256]
    float* out = (float*)d_out;                    // [32][512][64][64]
    float* Wp  = (float*)d_ws;                     // scratch: 32*512*128 fp32 = 8 MB

    wp_kernel<<<dim3(HD / 64, BB), 256, 0, stream>>>(Wmat, head_w, Wp);
    fused_kernel<<<dim3(BB * 64), 256, 0, stream>>>(H, Wp, out);
}

// Round 2
// 487.663 us; speedup vs baseline: 2.1464x; 2.1464x over previous
//
#include <hip/hip_runtime.h>

// Problem constants (from reference setup_inputs)
#define BB 32     // batch
#define TD 256    // t_dim
#define HD 512    // h_dim
#define MM 128    // M (words)
#define NN 4096   // h*w

typedef __attribute__((ext_vector_type(8))) short short8;
typedef __attribute__((ext_vector_type(4))) float floatx4;

__device__ inline unsigned int bf16_rne(float f) {
    unsigned int u = __float_as_uint(f);
    return (u + 0x7fffu + ((u >> 16) & 1u)) >> 16;
}
__device__ inline float quad16_max(float v) {
    v = fmaxf(v, __shfl_xor(v, 1));
    v = fmaxf(v, __shfl_xor(v, 2));
    v = fmaxf(v, __shfl_xor(v, 4));
    v = fmaxf(v, __shfl_xor(v, 8));
    return v;
}
__device__ inline float quad16_sum(float v) {
    v += __shfl_xor(v, 1);
    v += __shfl_xor(v, 2);
    v += __shfl_xor(v, 4);
    v += __shfl_xor(v, 8);
    return v;
}

// ---------------------------------------------------------------------------
// Kernel 1: Wp[b][h][m] = sum_t head_w[h][t] * W[b][t][m]  (fp32 GEMM, small)
// Emits MFMA-ready layouts:
//   Wpt_hi/Wpt_lo : bf16 [B][MM][HD]  (scores B-operand, h contiguous; hi=trunc16, lo=rne(x-hi))
//   Wp_b          : bf16 [B][HD][MM]  (PV B-operand, m contiguous, RNE)
// ---------------------------------------------------------------------------
__global__ __launch_bounds__(256, 2) void wp_kernel(
    const float* __restrict__ Wmat,     // [B][TD][MM]
    const float* __restrict__ head_w,   // [HD][TD]
    unsigned short* __restrict__ Wpt_hi,
    unsigned short* __restrict__ Wpt_lo,
    unsigned short* __restrict__ Wp_b)
{
    const int tid = threadIdx.x;
    const int tx = tid & 31;            // m group: m = tx*4 + c
    const int ty = tid >> 5;            // h group: h = ty*8 + r
    const int b  = blockIdx.y;
    const int h0 = blockIdx.x * 64;

    __shared__ float s_hw[64][64];      // [h][t]
    __shared__ float s_w[64][128];      // [t][m]

    float acc[8][4];
#pragma unroll
    for (int r = 0; r < 8; ++r)
#pragma unroll
        for (int c = 0; c < 4; ++c) acc[r][c] = 0.f;

    for (int t0 = 0; t0 < TD; t0 += 64) {
#pragma unroll
        for (int k = 0; k < 4; ++k) {
            int i = (tid >> 4) + 16 * k;
            int j = (tid & 15) * 4;
            *(float4*)&s_hw[i][j] = *(const float4*)&head_w[(h0 + i) * TD + t0 + j];
        }
#pragma unroll
        for (int k = 0; k < 8; ++k) {
            int i = (tid >> 5) + 8 * k;
            *(float4*)&s_w[i][(tid & 31) * 4] =
                *(const float4*)&Wmat[((b * TD) + t0 + i) * MM + (tid & 31) * 4];
        }
        __syncthreads();
#pragma unroll 4
        for (int tt = 0; tt < 64; ++tt) {
            float b4[4];
            *(float4*)b4 = *(const float4*)&s_w[tt][tx * 4];
#pragma unroll
            for (int r = 0; r < 8; ++r) {
                float a = s_hw[ty * 8 + r][tt];
#pragma unroll
                for (int c = 0; c < 4; ++c) acc[r][c] += a * b4[c];
            }
        }
        __syncthreads();
    }

    // ---- Wp_b store: bf16 [b][h][m], m contiguous ----
#pragma unroll
    for (int r = 0; r < 8; ++r) {
        unsigned int p0 = bf16_rne(acc[r][0]) | (bf16_rne(acc[r][1]) << 16);
        unsigned int p1 = bf16_rne(acc[r][2]) | (bf16_rne(acc[r][3]) << 16);
        uint2 v; v.x = p0; v.y = p1;
        *(uint2*)&Wp_b[((size_t)(b * HD) + h0 + ty * 8 + r) * MM + tx * 4] = v;
    }
    // ---- Wpt hi/lo store: bf16 [b][m][h], h contiguous (8 h per thread -> b128) ----
#pragma unroll
    for (int c = 0; c < 4; ++c) {
        unsigned int hw4[4], lw4[4];
#pragma unroll
        for (int rp = 0; rp < 4; ++rp) {
            float x0 = acc[2 * rp][c], x1 = acc[2 * rp + 1][c];
            unsigned int u0 = __float_as_uint(x0), u1 = __float_as_uint(x1);
            float l0 = x0 - __uint_as_float(u0 & 0xffff0000u);
            float l1 = x1 - __uint_as_float(u1 & 0xffff0000u);
            hw4[rp] = (u0 >> 16) | (u1 & 0xffff0000u);
            lw4[rp] = bf16_rne(l0) | (bf16_rne(l1) << 16);
        }
        size_t base = ((size_t)(b * MM) + tx * 4 + c) * HD + h0 + ty * 8;
        *(uint4*)&Wpt_hi[base] = make_uint4(hw4[0], hw4[1], hw4[2], hw4[3]);
        *(uint4*)&Wpt_lo[base] = make_uint4(lw4[0], lw4[1], lw4[2], lw4[3]);
    }
}

// ---------------------------------------------------------------------------
// Fused kernel: scores (bf16-split MFMA, K=512) -> softmax(M=128) -> PV (bf16
// MFMA, K=128) -> store out[h][n].  One block per (b, 128-row n-tile).
// 256 threads = 4 waves, 2x2 wave split in phase 1 (64n x 64m per wave).
// LDS 64KB total -> 2 blocks/CU. All tile layouts use 16B-unit XOR swizzle:
//   8-unit rows  (128B): elem (row,k): unit u=k>>3, stored at u^(row&7)
//   16-unit rows (256B): unit u=k>>3 stored at u^(row&15)
// -> staging writes, fragment b128 reads all bank-conflict-free (verified
//    by bank arithmetic; 8 word-accesses/bank = b128 minimum).
// ---------------------------------------------------------------------------
__global__ __launch_bounds__(256, 2) void fused_kernel(
    const float* __restrict__ H,              // [B][HD][NN]
    const unsigned short* __restrict__ Wpt_hi,// [B][MM][HD]
    const unsigned short* __restrict__ Wpt_lo,
    const unsigned short* __restrict__ Wp_b,  // [B][HD][MM]
    float* __restrict__ out)                  // [B][HD][NN]
{
    __shared__ __align__(16) unsigned char smem[65536];
    const int tid = threadIdx.x;
    const int w   = tid >> 6;
    const int L   = tid & 63;
    const int q   = L >> 4;
    const int l15 = L & 15;
    const int b   = blockIdx.y;
    const int n0  = blockIdx.x * 128;

    unsigned char* Ah = smem;           // [128n][8u]  bf16 hi of H^T tile
    unsigned char* Al = smem + 16384;   // lo
    unsigned char* Bh = smem + 32768;   // [128m][8u]  Wpt_hi tile
    unsigned char* Bl = smem + 49152;   // Wpt_lo tile

    const int nh = (w & 1) * 64;        // wave n-half (phase 1 & 2)
    const int mh = (w >> 1) * 64;       // wave m-half (phase 1)

    const float* Hb = H + ((size_t)b * HD) * NN + n0;
    const unsigned short* WptH = Wpt_hi + (size_t)b * MM * HD;
    const unsigned short* WptL = Wpt_lo + (size_t)b * MM * HD;

    floatx4 acc[4][4];
#pragma unroll
    for (int nt = 0; nt < 4; ++nt)
#pragma unroll
        for (int mt = 0; mt < 4; ++mt) acc[nt][mt] = (floatx4){0.f, 0.f, 0.f, 0.f};

    // staging coords for A (transpose H[h][n] -> Ah/Al[n][h])
    const int sa_n = (w & 1) * 64 + (tid & 63);  // n owned for staging
    const int sa_h = (w >> 1) * 32;              // h-half within chunk

    // ================= Phase 1: scores =================
    for (int hc = 0; hc < 8; ++hc) {
        const int h0 = hc * 64;
        // --- stage A: 8 coalesced b32 loads along n per 8-h run, split, b128 write ---
#pragma unroll
        for (int ii = 0; ii < 4; ++ii) {
            const int hh = sa_h + ii * 8;
            const float* src = Hb + (size_t)(h0 + hh) * NN + sa_n;
            unsigned int hp[4], lp[4];
#pragma unroll
            for (int jp = 0; jp < 4; ++jp) {
                float x0 = src[(size_t)(2 * jp) * NN];
                float x1 = src[(size_t)(2 * jp + 1) * NN];
                unsigned int u0 = __float_as_uint(x0), u1 = __float_as_uint(x1);
                float l0 = x0 - __uint_as_float(u0 & 0xffff0000u);
                float l1 = x1 - __uint_as_float(u1 & 0xffff0000u);
                hp[jp] = (u0 >> 16) | (u1 & 0xffff0000u);
                lp[jp] = bf16_rne(l0) | (bf16_rne(l1) << 16);
            }
            const int off = sa_n * 128 + (((hh >> 3) ^ (sa_n & 7)) * 16);
            *(uint4*)(Ah + off) = make_uint4(hp[0], hp[1], hp[2], hp[3]);
            *(uint4*)(Al + off) = make_uint4(lp[0], lp[1], lp[2], lp[3]);
        }
        // --- stage B: straight swizzled copy of Wpt hi/lo [m][h-chunk] ---
#pragma unroll
        for (int k = 0; k < 4; ++k) {
            int flat = tid + 256 * k;           // 0..1023 = 128 m-rows x 8 units
            int m = flat >> 3, u = flat & 7;
            size_t g = (size_t)m * HD + h0 + u * 8;
            uint4 vh = *(const uint4*)&WptH[g];
            uint4 vl = *(const uint4*)&WptL[g];
            int off = m * 128 + ((u ^ (m & 7)) * 16);
            *(uint4*)(Bh + off) = vh;
            *(uint4*)(Bl + off) = vl;
        }
        __syncthreads();
        // --- MFMA: 2 ksteps x 4x4 tiles x 3 split terms ---
#pragma unroll
        for (int ks = 0; ks < 2; ++ks) {
            short8 ahf[4], alf[4], bhf[4], blf[4];
#pragma unroll
            for (int nt = 0; nt < 4; ++nt) {
                int n = nh + nt * 16 + l15;
                int off = n * 128 + (((q + 4 * ks) ^ (n & 7)) * 16);
                ahf[nt] = *(short8*)(Ah + off);
                alf[nt] = *(short8*)(Al + off);
            }
#pragma unroll
            for (int mt = 0; mt < 4; ++mt) {
                int m = mh + mt * 16 + l15;
                int off = m * 128 + (((q + 4 * ks) ^ (m & 7)) * 16);
                bhf[mt] = *(short8*)(Bh + off);
                blf[mt] = *(short8*)(Bl + off);
            }
#pragma unroll
            for (int nt = 0; nt < 4; ++nt)
#pragma unroll
                for (int mt = 0; mt < 4; ++mt) {
                    acc[nt][mt] = __builtin_amdgcn_mfma_f32_16x16x32_bf16(ahf[nt], bhf[mt], acc[nt][mt], 0, 0, 0);
                    acc[nt][mt] = __builtin_amdgcn_mfma_f32_16x16x32_bf16(alf[nt], bhf[mt], acc[nt][mt], 0, 0, 0);
                    acc[nt][mt] = __builtin_amdgcn_mfma_f32_16x16x32_bf16(ahf[nt], blf[mt], acc[nt][mt], 0, 0, 0);
                }
        }
        __syncthreads();
    }

    // ================= Softmax over m (128) =================
    // lane holds D rows n = nh + nt*16 + q*4 + r, cols m = mh + mt*16 + l15
    float* redmax = (float*)(smem + 49152);          // [2][128]
    float* redsum = (float*)(smem + 49152 + 1024);   // [2][128]
    const int mhalf = w >> 1;

    float rmax[4][4];
#pragma unroll
    for (int nt = 0; nt < 4; ++nt)
#pragma unroll
        for (int r = 0; r < 4; ++r) {
            float v = fmaxf(fmaxf(acc[nt][0][r], acc[nt][1][r]),
                            fmaxf(acc[nt][2][r], acc[nt][3][r]));
            rmax[nt][r] = quad16_max(v);
        }
    if (l15 == 0) {
#pragma unroll
        for (int nt = 0; nt < 4; ++nt)
#pragma unroll
            for (int r = 0; r < 4; ++r)
                redmax[mhalf * 128 + nh + nt * 16 + q * 4 + r] = rmax[nt][r];
    }
    __syncthreads();
    float gmax[4][4], rsum[4][4];
#pragma unroll
    for (int nt = 0; nt < 4; ++nt)
#pragma unroll
        for (int r = 0; r < 4; ++r) {
            gmax[nt][r] = fmaxf(rmax[nt][r],
                                redmax[(1 - mhalf) * 128 + nh + nt * 16 + q * 4 + r]);
            float s = 0.f;
#pragma unroll
            for (int mt = 0; mt < 4; ++mt) {
                float e = __expf(acc[nt][mt][r] - gmax[nt][r]);
                acc[nt][mt][r] = e;
                s += e;
            }
            rsum[nt][r] = quad16_sum(s);
        }
    if (l15 == 0) {
#pragma unroll
        for (int nt = 0; nt < 4; ++nt)
#pragma unroll
            for (int r = 0; r < 4; ++r)
                redsum[mhalf * 128 + nh + nt * 16 + q * 4 + r] = rsum[nt][r];
    }
    __syncthreads();

    // write A_soft (bf16) to LDS [128n][16u] swizzled
    unsigned char* As = smem;           // reuses Ah/Al area (32KB)
#pragma unroll
    for (int nt = 0; nt < 4; ++nt)
#pragma unroll
        for (int r = 0; r < 4; ++r) {
            int n = nh + nt * 16 + q * 4 + r;
            float inv = 1.f / (rsum[nt][r] + redsum[(1 - mhalf) * 128 + n]);
#pragma unroll
            for (int mt = 0; mt < 4; ++mt) {
                int m = mh + mt * 16 + l15;
                unsigned short v = (unsigned short)bf16_rne(acc[nt][mt][r] * inv);
                *(unsigned short*)(As + n * 256 + (((m >> 3) ^ (n & 15)) * 16) + (m & 7) * 2) = v;
            }
        }
    __syncthreads();

    // ================= Phase 2: PV =================
    // wave: n-half nh (as phase 1), h-quarter hq within each 64-h chunk
    const int hq = (w >> 1) * 32;
    unsigned char* Wpb = smem + 32768;  // [64h][16u] bf16
    const unsigned short* WpB = Wp_b + (size_t)b * HD * MM;
    float* outb = out + ((size_t)b * HD) * NN + n0;

    // preload A-fragments (reused across all 8 h-chunks)
    short8 af[4][4];                    // [nt][ks]
#pragma unroll
    for (int nt = 0; nt < 4; ++nt)
#pragma unroll
        for (int ks = 0; ks < 4; ++ks) {
            int n = nh + nt * 16 + l15;
            af[nt][ks] = *(short8*)(As + n * 256 + (((q + 4 * ks) ^ (n & 15)) * 16));
        }

    for (int hc = 0; hc < 8; ++hc) {
        // stage Wp_b chunk [64h][128m] (straight swizzled copy)
#pragma unroll
        for (int k = 0; k < 4; ++k) {
            int flat = tid + 256 * k;           // 0..1023 = 64 h-rows x 16 units
            int hrow = flat >> 4, u = flat & 15;
            uint4 v = *(const uint4*)&WpB[(size_t)(hc * 64 + hrow) * MM + u * 8];
            *(uint4*)(Wpb + hrow * 256 + ((u ^ (hrow & 15)) * 16)) = v;
        }
        __syncthreads();

        floatx4 accB[4][2];
#pragma unroll
        for (int nt = 0; nt < 4; ++nt)
#pragma unroll
            for (int ht = 0; ht < 2; ++ht) accB[nt][ht] = (floatx4){0.f, 0.f, 0.f, 0.f};

#pragma unroll
        for (int ks = 0; ks < 4; ++ks) {
            short8 bf[2];
#pragma unroll
            for (int ht = 0; ht < 2; ++ht) {
                int hl = hq + ht * 16 + l15;
                bf[ht] = *(short8*)(Wpb + hl * 256 + (((q + 4 * ks) ^ (hl & 15)) * 16));
            }
#pragma unroll
            for (int nt = 0; nt < 4; ++nt)
#pragma unroll
                for (int ht = 0; ht < 2; ++ht)
                    accB[nt][ht] = __builtin_amdgcn_mfma_f32_16x16x32_bf16(af[nt][ks], bf[ht], accB[nt][ht], 0, 0, 0);
        }
        // store D[n][h] -> out[h][n]: lane = col h, 4 consecutive rows n -> float4
#pragma unroll
        for (int nt = 0; nt < 4; ++nt)
#pragma unroll
            for (int ht = 0; ht < 2; ++ht) {
                int hglob = hc * 64 + hq + ht * 16 + l15;
                int nrow = nh + nt * 16 + q * 4;
                *(floatx4*)(outb + (size_t)hglob * NN + nrow) = accB[nt][ht];
            }
        __syncthreads();
    }
}

// ---------------------------------------------------------------------------
extern "C" void kernel_launch(void* const* d_in, const int* in_sizes, int n_in,
                              void* d_out, int out_size, void* d_ws, size_t ws_size,
                              hipStream_t stream)
{
    (void)in_sizes; (void)n_in; (void)out_size; (void)ws_size;
    const float* H      = (const float*)d_in[0];   // [32][512][64][64]
    const float* Wmat   = (const float*)d_in[1];   // [32][256][128]
    const float* head_w = (const float*)d_in[2];   // [512][256]
    float* out = (float*)d_out;                    // [32][512][64][64]

    // ws layout (12 MB total):
    unsigned short* Wpt_hi = (unsigned short*)d_ws;                    // 4 MB
    unsigned short* Wpt_lo = Wpt_hi + (size_t)BB * MM * HD;            // 4 MB
    unsigned short* Wp_b   = Wpt_lo + (size_t)BB * MM * HD;            // 4 MB

    wp_kernel<<<dim3(HD / 64, BB), 256, 0, stream>>>(Wmat, head_w, Wpt_hi, Wpt_lo, Wp_b);
    fused_kernel<<<dim3(NN / 128, BB), 256, 0, stream>>>(H, Wpt_hi, Wpt_lo, Wp_b, out);
}